// Round 11
// baseline (75.874 us; speedup 1.0000x reference)
//
#include <hip/hip_runtime.h>
#include <hip/hip_bf16.h>
#include <stdint.h>

typedef float  f32x4   __attribute__((ext_vector_type(4)));
typedef __bf16 bf16x8  __attribute__((ext_vector_type(8)));
typedef __bf16 bf16x4  __attribute__((ext_vector_type(4)));

#define LOG2E 1.44269504088896340736f

__device__ __forceinline__ f32x4 mfma16(bf16x8 a, bf16x8 b, f32x4 c) {
    return __builtin_amdgcn_mfma_f32_16x16x32_bf16(a, b, c, 0, 0, 0);
}

__device__ __forceinline__ float fast_exp2(float x) {
#if __has_builtin(__builtin_amdgcn_exp2f)
    return __builtin_amdgcn_exp2f(x);
#else
    return exp2f(x);
#endif
}

// async global->LDS, 16B per lane (wave-uniform base + lane*16 dest).
__device__ __forceinline__ void gload16(const void* g, void* lds) {
    __builtin_amdgcn_global_load_lds(
        (const __attribute__((address_space(1))) uint32_t*)g,
        (__attribute__((address_space(3))) uint32_t*)lds, 16, 0, 0);
}

// ---------------- fused preprocessing: cast_pool + cast_w + maskscan ----------------
// id < 1024          : cast(hs)->hsb + avgpool->poolb  (one read of hs)
// 1024 <= id < 2560  : weight casts (Wq*qscale -> wqb, Wk/Wv -> wkvb)
// id in {2560, 2561} : mask scan for batch id-2560
__global__ __launch_bounds__(256)
void prep_kernel(const float* __restrict__ hs, const int* __restrict__ mask,
                 const float* __restrict__ Wq, const float* __restrict__ Wk,
                 const float* __restrict__ Wv,
                 __bf16* __restrict__ hsb, __bf16* __restrict__ poolb,
                 __bf16* __restrict__ wqb, __bf16* __restrict__ wkvb,
                 int* __restrict__ idxl, float* __restrict__ bias_c,
                 int* __restrict__ meta, float qscale) {
    const int id = blockIdx.x;
    const int t  = threadIdx.x;

    if (id < 1024) {
        // ---- cast + pool ----
        int i = id * 256 + t;
        int j = i >> 7;
        int c = (i & 127) * 8;
        int b = j >> 10, tt = j & 1023;
        size_t rowg = (size_t)(b * 4096 + tt * 4);
        const float* base = hs + (rowg << 10) + c;
        float sum[8];
#pragma unroll
        for (int e = 0; e < 8; ++e) sum[e] = 0.f;
#pragma unroll
        for (int r = 0; r < 4; ++r) {
            float4 a = *(const float4*)(base + (size_t)r * 1024);
            float4 d = *(const float4*)(base + (size_t)r * 1024 + 4);
            bf16x8 o;
            o[0] = (__bf16)a.x; o[1] = (__bf16)a.y; o[2] = (__bf16)a.z; o[3] = (__bf16)a.w;
            o[4] = (__bf16)d.x; o[5] = (__bf16)d.y; o[6] = (__bf16)d.z; o[7] = (__bf16)d.w;
            *reinterpret_cast<bf16x8*>(hsb + ((rowg + r) << 10) + c) = o;
            sum[0] += a.x; sum[1] += a.y; sum[2] += a.z; sum[3] += a.w;
            sum[4] += d.x; sum[5] += d.y; sum[6] += d.z; sum[7] += d.w;
        }
        bf16x8 p;
#pragma unroll
        for (int e = 0; e < 8; ++e) p[e] = (__bf16)(sum[e] * 0.25f);
        *reinterpret_cast<bf16x8*>(poolb + ((size_t)j << 10) + c) = p;
    } else if (id < 2560) {
        // ---- weight casts ----
        int i = (id - 1024) * 256 + t;
        const float* src; __bf16* dst; float sc; int j;
        if (i < 131072)      { src = Wq; dst = wqb;            sc = qscale; j = i; }
        else if (i < 262144) { src = Wk; dst = wkvb;           sc = 1.f;    j = i - 131072; }
        else                 { src = Wv; dst = wkvb + 1048576; sc = 1.f;    j = i - 262144; }
        const float4* s = reinterpret_cast<const float4*>(src) + (size_t)j * 2;
        float4 a = s[0], b = s[1];
        bf16x8 o;
        o[0] = (__bf16)(a.x * sc); o[1] = (__bf16)(a.y * sc);
        o[2] = (__bf16)(a.z * sc); o[3] = (__bf16)(a.w * sc);
        o[4] = (__bf16)(b.x * sc); o[5] = (__bf16)(b.y * sc);
        o[6] = (__bf16)(b.z * sc); o[7] = (__bf16)(b.w * sc);
        *reinterpret_cast<bf16x8*>(dst + (size_t)j * 8) = o;
    } else {
        // ---- mask scan (batch b = id-2560). Bucket unmasked iff all 4 raw
        // positions are 0. Masked -> -10000 bias -> exp underflows to EXACTLY
        // 0 in f32 (reference identical after max-subtract) -> compaction is
        // bit-exact. cnt==0 fallback: identity list + sscale=0 -> uniform.
        const int b = id - 2560;
        __shared__ int ps[256];
        __shared__ int totsh;
        int f[4];
        const int4* mp = (const int4*)(mask + b * 4096 + t * 16);
#pragma unroll
        for (int i = 0; i < 4; ++i) {
            int4 v = mp[i];
            f[i] = ((v.x | v.y | v.z | v.w) == 0) ? 1 : 0;
        }
        int c = f[0] + f[1] + f[2] + f[3];
        ps[t] = c;
        __syncthreads();
        for (int off = 1; off < 256; off <<= 1) {
            int v = (t >= off) ? ps[t - off] : 0;
            __syncthreads();
            ps[t] += v;
            __syncthreads();
        }
        int excl = ps[t] - c;
        if (t == 255) totsh = ps[255];
        __syncthreads();
        int cnt = totsh;
        int e = excl;
#pragma unroll
        for (int i = 0; i < 4; ++i)
            if (f[i]) idxl[b * 1024 + (e++)] = t * 4 + i;
        int cntf = cnt ? cnt : 1024;
        if (cnt == 0) {
#pragma unroll
            for (int i = 0; i < 4; ++i) idxl[b * 1024 + t * 4 + i] = t * 4 + i;
        }
        int ntiles = (cntf + 63) >> 6;
#pragma unroll
        for (int i = 0; i < 4; ++i) {
            int j = t * 4 + i;
            bias_c[b * 1024 + j] = (j < cntf) ? 0.f : -14427.0f;
        }
        if (t == 0) {
            meta[b * 4 + 0] = cntf;
            meta[b * 4 + 1] = ntiles;
            meta[b * 4 + 2] = ntiles << 6;
            meta[b * 4 + 3] = __float_as_int(cnt ? 1.f : 0.f);
        }
    }
}

// ---------------- fused Q + compacted-KV GEMM, BK=32 double-buffered ----------------
// id<512: Q path (hsb@wqb^T -> qb). id>=512: KV path over COMPACTED pooled rows.
// vs r10: BK 64->32 with 2x LDS buffers -- LDS stays 32 KB total (r9 lesson: 64 KB
// serialized a 3rd dispatch wave), one barrier/K-step, each vmcnt drain covered by
// the previous step's compute. K-order of summation unchanged -> bit-identical.
// 64B LDS rows only admit a 4-slot swizzle ^((r&3)<<4) -> 4-way ds_read conflict
// (1.58x on a non-critical pipe) -- accepted.
// XCD swizzle: 768 = 8*96, lid = (bid&7)*96 + bid>>3 groups 96 consecutive logical
// blocks per XCD (weight panels L2-resident per XCD).
__global__ __launch_bounds__(256)
void gemm_fused(const __bf16* __restrict__ hsb, const __bf16* __restrict__ poolb,
                const __bf16* __restrict__ wqb, const __bf16* __restrict__ wkvb,
                const float* __restrict__ bq, const float* __restrict__ bk,
                const float* __restrict__ bv, float qscale,
                const int* __restrict__ idxl, const int* __restrict__ meta,
                __bf16* __restrict__ qb, __bf16* __restrict__ kb,
                __bf16* __restrict__ vtb) {
    __shared__ __bf16 As[2][128 * 32];
    __shared__ __bf16 Bs[2][128 * 32];
    const int tid  = threadIdx.x;
    const int lane = tid & 63, wid = tid >> 6;
    const int lg = lane >> 4, l15 = lane & 15;
    const int wm = (wid >> 1) * 64, wn = (wid & 1) * 64;

    const int id = (blockIdx.x & 7) * 96 + (blockIdx.x >> 3);   // XCD-chunked, bijective
    const bool isQ = (id < 512);
    int bx, by, bB = 0, cntf = 0;
    if (isQ) { bx = id & 63; by = id >> 6; }
    else {
        int lid = id - 512;
        bB = lid >> 7;
        bx = (lid >> 4) & 7;
        by = lid & 15;
        if (bx * 128 >= meta[bB * 4 + 2]) return;   // beyond needed compact rows
        cntf = meta[bB * 4 + 0];
    }
    const int rowBase = bx * 128, colBase = by * 128;

    const f32x4 zero = {0.f, 0.f, 0.f, 0.f};
    f32x4 acc[4][4];
#pragma unroll
    for (int m = 0; m < 4; ++m)
#pragma unroll
        for (int n = 0; n < 4; ++n) acc[m][n] = zero;

    const __bf16* W = isQ ? wqb : wkvb;
    const char* Wg = (const char*)(W + (size_t)colBase * 1024);

    // staging geometry: 8 KB per matrix per K-step = 2 chunks of 16B per thread.
    // 64B rows: r = o>>6 (4 lanes/row), cb = o&63, swizzle ^((r&3)<<4).
    const char* ag[2]; const char* wg[2]; int ld[2];
#pragma unroll
    for (int p = 0; p < 2; ++p) {
        int o  = p * 4096 + tid * 16;
        int r  = o >> 6, cb = o & 63;
        int cs = cb ^ ((r & 3) << 4);
        if (isQ) {
            ag[p] = (const char*)(hsb + (size_t)(rowBase + r) * 1024) + cs;
        } else {
            int rg   = rowBase + r;
            int idxg = idxl[bB * 1024 + (rg < cntf ? rg : cntf - 1)];
            ag[p] = (const char*)(poolb + (size_t)(bB * 1024 + idxg) * 1024) + cs;
        }
        wg[p] = Wg + (size_t)r * 2048 + cs;
        ld[p] = o;
    }

    // prologue: stage K-step 0 -> buf 0
#pragma unroll
    for (int p = 0; p < 2; ++p) {
        gload16(ag[p], (char*)As[0] + ld[p]);
        gload16(wg[p], (char*)Bs[0] + ld[p]);
    }

    int cur = 0;
    for (int kt = 0; kt < 32; ++kt) {
        __syncthreads();   // buf[cur] ready (vmcnt drained; loads had full prev step to land)
        if (kt < 31) {
            const int k0b = (kt + 1) * 64;   // 32 bf16 = 64 bytes per step
#pragma unroll
            for (int p = 0; p < 2; ++p) {
                gload16(ag[p] + k0b, (char*)As[cur ^ 1] + ld[p]);
                gload16(wg[p] + k0b, (char*)Bs[cur ^ 1] + ld[p]);
            }
        }
        const char* AsB = (const char*)As[cur];
        const char* BsB = (const char*)Bs[cur];

        bf16x8 af[4], bfr[4];
#pragma unroll
        for (int m = 0; m < 4; ++m) {
            int r = wm + m * 16 + l15;
            af[m] = *(const bf16x8*)(AsB + r * 64 + ((lg * 16) ^ ((r & 3) << 4)));
        }
#pragma unroll
        for (int n = 0; n < 4; ++n) {
            int r = wn + n * 16 + l15;
            bfr[n] = *(const bf16x8*)(BsB + r * 64 + ((lg * 16) ^ ((r & 3) << 4)));
        }
#pragma unroll
        for (int m = 0; m < 4; ++m)
#pragma unroll
            for (int n = 0; n < 4; ++n)
                acc[m][n] = mfma16(af[m], bfr[n], acc[m][n]);
        cur ^= 1;
    }

    // epilogue. C layout: col = lane&15, row = (lane>>4)*4 + reg
#pragma unroll
    for (int m = 0; m < 4; ++m)
#pragma unroll
        for (int n = 0; n < 4; ++n) {
            int col  = colBase + wn + n * 16 + l15;
            int row0 = rowBase + wm + m * 16 + lg * 4;
            if (isQ) {
                float bvl = bq[col] * qscale;
#pragma unroll
                for (int reg = 0; reg < 4; ++reg)
                    qb[(size_t)(row0 + reg) * 1024 + col] = (__bf16)(acc[m][n][reg] + bvl);
            } else if (col < 1024) {
                float bvl = bk[col];
#pragma unroll
                for (int reg = 0; reg < 4; ++reg)
                    kb[(size_t)(bB * 1024 + row0 + reg) * 1024 + col] = (__bf16)(acc[m][n][reg] + bvl);
            } else {
                float bvl = bv[col - 1024];
                bf16x4 o;
#pragma unroll
                for (int reg = 0; reg < 4; ++reg) o[reg] = (__bf16)(acc[m][n][reg] + bvl);
                *reinterpret_cast<bf16x4*>(vtb + ((size_t)(bB * 1024 + (col - 1024)) << 10) + row0) = o;
            }
        }
}

// ---------------- flash attention over COMPACTED keys (unchanged from r8) ----------------
__global__ __launch_bounds__(256, 2)
void attn_kernel(const __bf16* __restrict__ Q, const __bf16* __restrict__ K,
                 const __bf16* __restrict__ Vt, const float* __restrict__ bias_c,
                 const int* __restrict__ meta, float* __restrict__ out) {
    __shared__ __bf16 Ks[2][64 * 64];
    __shared__ __bf16 Vs[2][64 * 64];
    __shared__ __bf16 Ps[4][64 * 64];
    const int tid  = threadIdx.x;
    const int lane = tid & 63, wid = tid >> 6;
    const int lg = lane >> 4, l15 = lane & 15;

    // XCD-aware bijective swizzle (512 blocks, 64 consecutive per XCD)
    const int lin = blockIdx.x + blockIdx.y * 16;
    const int nid = (lin & 7) * 64 + (lin >> 3);
    const int qi = nid & 15, bh = nid >> 4;
    const int b = bh >> 4, h = bh & 15;
    const int qbase = qi * 256;

    const int   ntile  = meta[b * 4 + 1];
    const float sscale = __int_as_float(meta[b * 4 + 3]);

    // Q fragments: 4 sub-tiles of 16 q rows each (A layout: row=l15, k=lg*8+j)
    bf16x8 aq[4][2];
#pragma unroll
    for (int qm = 0; qm < 4; ++qm) {
        const __bf16* qrow = Q + (((size_t)(b * 4096 + qbase + wid * 64 + qm * 16 + l15)) << 10) + h * 64;
        aq[qm][0] = *(const bf16x8*)(qrow + lg * 8);
        aq[qm][1] = *(const bf16x8*)(qrow + 32 + lg * 8);
    }

    const f32x4 zero = {0.f, 0.f, 0.f, 0.f};
    f32x4 acc[4][4];
#pragma unroll
    for (int qm = 0; qm < 4; ++qm)
#pragma unroll
        for (int n = 0; n < 4; ++n) acc[qm][n] = zero;
    float rs[4] = {0.f, 0.f, 0.f, 0.f};

    const char* Kg = (const char*)(K + (((size_t)(b * 1024)) << 10) + h * 64);
    const char* Vg = (const char*)(Vt + (((size_t)(b * 1024 + h * 64)) << 10));
    const float* mbp = bias_c + b * 1024;

    char* PsB = (char*)Ps[wid];
    const int pswz = (l15 & 7) << 4;

    const char* kg[2]; const char* vg[2]; int ld[2];
#pragma unroll
    for (int p = 0; p < 2; ++p) {
        int o  = p * 4096 + tid * 16;
        int r  = o >> 7, cb = o & 127;
        int cs = cb ^ ((r & 7) << 4);
        kg[p] = Kg + (size_t)r * 2048 + cs;
        vg[p] = Vg + (size_t)r * 2048 + cs;
        ld[p] = o;
    }

#pragma unroll
    for (int p = 0; p < 2; ++p) {
        gload16(kg[p], (char*)Ks[0] + ld[p]);
        gload16(vg[p], (char*)Vs[0] + ld[p]);
    }

    int cur = 0;
    for (int kt = 0; kt < ntile; ++kt) {
        __syncthreads();   // buf[cur] ready (vmcnt drained at barrier), buf[cur^1] free
        if (kt + 1 < ntile) {
#pragma unroll
            for (int p = 0; p < 2; ++p) {
                gload16(kg[p] + (size_t)(kt + 1) * 131072, (char*)Ks[cur ^ 1] + ld[p]);
                gload16(vg[p] + (kt + 1) * 128,            (char*)Vs[cur ^ 1] + ld[p]);
            }
        }
        const char* KsB = (const char*)Ks[cur];
        const char* VsB = (const char*)Vs[cur];

        // K fragments (reused across 4 q sub-tiles)
        bf16x8 bk[4][2];
#pragma unroll
        for (int n = 0; n < 4; ++n)
#pragma unroll
            for (int kk = 0; kk < 2; ++kk) {
                int key = n * 16 + l15;
                bk[n][kk] = *(const bf16x8*)(KsB + key * 128 + ((kk * 64 + lg * 16) ^ ((key & 7) << 4)));
            }
        f32x4 mv[4];
#pragma unroll
        for (int n = 0; n < 4; ++n) mv[n] = *(const f32x4*)(mbp + kt * 64 + n * 16 + lg * 4);

        // per q sub-tile: S^T = K·Q^T (col=q=l15, row=key=lg*4+reg), exp2, write P
#pragma unroll
        for (int qm = 0; qm < 4; ++qm) {
            f32x4 s[4];
#pragma unroll
            for (int n = 0; n < 4; ++n) {
                s[n] = mfma16(bk[n][0], aq[qm][0], zero);
                s[n] = mfma16(bk[n][1], aq[qm][1], s[n]);
            }
            const int prow = (qm * 16 + l15) * 128;
#pragma unroll
            for (int n = 0; n < 4; ++n) {
                float p0 = fast_exp2(fmaf(s[n][0], sscale, mv[n][0]));
                float p1 = fast_exp2(fmaf(s[n][1], sscale, mv[n][1]));
                float p2 = fast_exp2(fmaf(s[n][2], sscale, mv[n][2]));
                float p3 = fast_exp2(fmaf(s[n][3], sscale, mv[n][3]));
                rs[qm] += (p0 + p1) + (p2 + p3);
                bf16x4 o;
                o[0] = (__bf16)p0; o[1] = (__bf16)p1; o[2] = (__bf16)p2; o[3] = (__bf16)p3;
                *(bf16x4*)(PsB + prow + ((n * 32 + lg * 8) ^ pswz)) = o;
            }
        }

        // V fragments (reused across 4 q sub-tiles)
        bf16x8 bv[4][2];
#pragma unroll
        for (int n = 0; n < 4; ++n)
#pragma unroll
            for (int kk = 0; kk < 2; ++kk) {
                int d = n * 16 + l15;
                bv[n][kk] = *(const bf16x8*)(VsB + d * 128 + ((kk * 64 + lg * 16) ^ ((d & 7) << 4)));
            }
#pragma unroll
        for (int qm = 0; qm < 4; ++qm) {
            const int prow = (qm * 16 + l15) * 128;
            bf16x8 ap0 = *(const bf16x8*)(PsB + prow + ((lg * 16) ^ pswz));
            bf16x8 ap1 = *(const bf16x8*)(PsB + prow + ((64 + lg * 16) ^ pswz));
#pragma unroll
            for (int n = 0; n < 4; ++n) {
                acc[qm][n] = mfma16(ap0, bv[n][0], acc[qm][n]);
                acc[qm][n] = mfma16(ap1, bv[n][1], acc[qm][n]);
            }
        }
        cur ^= 1;
    }

    // reduce row sums over the 4 lane-groups, redistribute to epilogue layout
    float inv[4][4];
#pragma unroll
    for (int qm = 0; qm < 4; ++qm) {
        rs[qm] += __shfl_xor(rs[qm], 16);
        rs[qm] += __shfl_xor(rs[qm], 32);
#pragma unroll
        for (int r = 0; r < 4; ++r) inv[qm][r] = 1.0f / __shfl(rs[qm], lg * 4 + r);
    }

#pragma unroll
    for (int qm = 0; qm < 4; ++qm)
#pragma unroll
        for (int n = 0; n < 4; ++n)
#pragma unroll
            for (int r = 0; r < 4; ++r) {
                size_t row = (size_t)(b * 4096 + qbase + wid * 64 + qm * 16 + lg * 4 + r);
                out[(row << 10) + h * 64 + n * 16 + l15] = acc[qm][n][r] * inv[qm][r];
            }
}

extern "C" void kernel_launch(void* const* d_in, const int* in_sizes, int n_in,
                              void* d_out, int out_size, void* d_ws, size_t ws_size,
                              hipStream_t stream) {
    const float* hs    = (const float*)d_in[0];
    const int*   amask = (const int*)d_in[1];
    const float* Wq    = (const float*)d_in[2];
    const float* bq    = (const float*)d_in[3];
    const float* Wk    = (const float*)d_in[4];
    const float* bk    = (const float*)d_in[5];
    const float* Wv    = (const float*)d_in[6];
    const float* bv    = (const float*)d_in[7];
    float* out = (float*)d_out;

    char* ws = (char*)d_ws;
    size_t off = 0;
    auto alloc = [&](size_t bytes) -> char* {
        char* p = ws + off;
        off += (bytes + 255) & ~(size_t)255;
        return p;
    };
    __bf16* hsb   = (__bf16*)alloc(8388608ull * 2);  // hidden bf16 [8192][1024]
    __bf16* qb    = (__bf16*)alloc(8388608ull * 2);  // Q bf16 (pre-scaled)
    __bf16* poolb = (__bf16*)alloc(2097152ull * 2);  // pooled bf16 [2048][1024]
    __bf16* kb    = (__bf16*)alloc(2097152ull * 2);  // K compact [b][key_c][1024]
    __bf16* vtb   = (__bf16*)alloc(2097152ull * 2);  // V^T compact [b][h*64+d][key_c]
    __bf16* wqb   = (__bf16*)alloc(1048576ull * 2);  // Wq * qscale
    __bf16* wkvb  = (__bf16*)alloc(2097152ull * 2);  // [Wk ; Wv]
    int*    idxl  = (int*)alloc(2048 * 4);           // compact index lists
    float*  biasc = (float*)alloc(2048 * 4);         // tail-validity bias
    int*    meta  = (int*)alloc(8 * 4);

    const float qscale = 0.125f * LOG2E;   // 1/sqrt(DH) and log2(e) folded into Q

    prep_kernel<<<2562, 256, 0, stream>>>(hs, amask, Wq, Wk, Wv, hsb, poolb,
                                          wqb, wkvb, idxl, biasc, meta, qscale);

    gemm_fused<<<768, 256, 0, stream>>>(hsb, poolb, wqb, wkvb, bq, bk, bv, qscale,
                                        idxl, meta, qb, kb, vtb);

    attn_kernel<<<dim3(16, 32), 256, 0, stream>>>(qb, kb, vtb, biasc, meta, out);
}

// Round 12
// 64.608 us; speedup vs baseline: 1.1744x; 1.1744x over previous
//
#include <hip/hip_runtime.h>
#include <hip/hip_bf16.h>
#include <stdint.h>

typedef float  f32x4   __attribute__((ext_vector_type(4)));
typedef __bf16 bf16x8  __attribute__((ext_vector_type(8)));
typedef __bf16 bf16x4  __attribute__((ext_vector_type(4)));

#define LOG2E 1.44269504088896340736f

__device__ __forceinline__ f32x4 mfma16(bf16x8 a, bf16x8 b, f32x4 c) {
    return __builtin_amdgcn_mfma_f32_16x16x32_bf16(a, b, c, 0, 0, 0);
}

__device__ __forceinline__ float fast_exp2(float x) {
#if __has_builtin(__builtin_amdgcn_exp2f)
    return __builtin_amdgcn_exp2f(x);
#else
    return exp2f(x);
#endif
}

// async global->LDS, 16B per lane (wave-uniform base + lane*16 dest).
__device__ __forceinline__ void gload16(const void* g, void* lds) {
    __builtin_amdgcn_global_load_lds(
        (const __attribute__((address_space(1))) uint32_t*)g,
        (__attribute__((address_space(3))) uint32_t*)lds, 16, 0, 0);
}

// ---------------- fused preprocessing: cast_pool + cast_w + maskscan ----------------
// id < 1024          : cast(hs)->hsb + avgpool->poolb  (one read of hs)
// 1024 <= id < 2560  : weight casts (Wq*qscale -> wqb, Wk/Wv -> wkvb)
// id in {2560, 2561} : mask scan for batch id-2560
__global__ __launch_bounds__(256)
void prep_kernel(const float* __restrict__ hs, const int* __restrict__ mask,
                 const float* __restrict__ Wq, const float* __restrict__ Wk,
                 const float* __restrict__ Wv,
                 __bf16* __restrict__ hsb, __bf16* __restrict__ poolb,
                 __bf16* __restrict__ wqb, __bf16* __restrict__ wkvb,
                 int* __restrict__ idxl, float* __restrict__ bias_c,
                 int* __restrict__ meta, float qscale) {
    const int id = blockIdx.x;
    const int t  = threadIdx.x;

    if (id < 1024) {
        // ---- cast + pool ----
        int i = id * 256 + t;
        int j = i >> 7;
        int c = (i & 127) * 8;
        int b = j >> 10, tt = j & 1023;
        size_t rowg = (size_t)(b * 4096 + tt * 4);
        const float* base = hs + (rowg << 10) + c;
        float sum[8];
#pragma unroll
        for (int e = 0; e < 8; ++e) sum[e] = 0.f;
#pragma unroll
        for (int r = 0; r < 4; ++r) {
            float4 a = *(const float4*)(base + (size_t)r * 1024);
            float4 d = *(const float4*)(base + (size_t)r * 1024 + 4);
            bf16x8 o;
            o[0] = (__bf16)a.x; o[1] = (__bf16)a.y; o[2] = (__bf16)a.z; o[3] = (__bf16)a.w;
            o[4] = (__bf16)d.x; o[5] = (__bf16)d.y; o[6] = (__bf16)d.z; o[7] = (__bf16)d.w;
            *reinterpret_cast<bf16x8*>(hsb + ((rowg + r) << 10) + c) = o;
            sum[0] += a.x; sum[1] += a.y; sum[2] += a.z; sum[3] += a.w;
            sum[4] += d.x; sum[5] += d.y; sum[6] += d.z; sum[7] += d.w;
        }
        bf16x8 p;
#pragma unroll
        for (int e = 0; e < 8; ++e) p[e] = (__bf16)(sum[e] * 0.25f);
        *reinterpret_cast<bf16x8*>(poolb + ((size_t)j << 10) + c) = p;
    } else if (id < 2560) {
        // ---- weight casts ----
        int i = (id - 1024) * 256 + t;
        const float* src; __bf16* dst; float sc; int j;
        if (i < 131072)      { src = Wq; dst = wqb;            sc = qscale; j = i; }
        else if (i < 262144) { src = Wk; dst = wkvb;           sc = 1.f;    j = i - 131072; }
        else                 { src = Wv; dst = wkvb + 1048576; sc = 1.f;    j = i - 262144; }
        const float4* s = reinterpret_cast<const float4*>(src) + (size_t)j * 2;
        float4 a = s[0], b = s[1];
        bf16x8 o;
        o[0] = (__bf16)(a.x * sc); o[1] = (__bf16)(a.y * sc);
        o[2] = (__bf16)(a.z * sc); o[3] = (__bf16)(a.w * sc);
        o[4] = (__bf16)(b.x * sc); o[5] = (__bf16)(b.y * sc);
        o[6] = (__bf16)(b.z * sc); o[7] = (__bf16)(b.w * sc);
        *reinterpret_cast<bf16x8*>(dst + (size_t)j * 8) = o;
    } else {
        // ---- mask scan (batch b = id-2560). Bucket unmasked iff all 4 raw
        // positions are 0. Masked -> -10000 bias -> exp underflows to EXACTLY
        // 0 in f32 (reference identical after max-subtract) -> compaction is
        // bit-exact. cnt==0 fallback: identity list + sscale=0 -> uniform.
        const int b = id - 2560;
        __shared__ int ps[256];
        __shared__ int totsh;
        int f[4];
        const int4* mp = (const int4*)(mask + b * 4096 + t * 16);
#pragma unroll
        for (int i = 0; i < 4; ++i) {
            int4 v = mp[i];
            f[i] = ((v.x | v.y | v.z | v.w) == 0) ? 1 : 0;
        }
        int c = f[0] + f[1] + f[2] + f[3];
        ps[t] = c;
        __syncthreads();
        for (int off = 1; off < 256; off <<= 1) {
            int v = (t >= off) ? ps[t - off] : 0;
            __syncthreads();
            ps[t] += v;
            __syncthreads();
        }
        int excl = ps[t] - c;
        if (t == 255) totsh = ps[255];
        __syncthreads();
        int cnt = totsh;
        int e = excl;
#pragma unroll
        for (int i = 0; i < 4; ++i)
            if (f[i]) idxl[b * 1024 + (e++)] = t * 4 + i;
        int cntf = cnt ? cnt : 1024;
        if (cnt == 0) {
#pragma unroll
            for (int i = 0; i < 4; ++i) idxl[b * 1024 + t * 4 + i] = t * 4 + i;
        }
        int ntiles = (cntf + 63) >> 6;
#pragma unroll
        for (int i = 0; i < 4; ++i) {
            int j = t * 4 + i;
            bias_c[b * 1024 + j] = (j < cntf) ? 0.f : -14427.0f;
        }
        if (t == 0) {
            meta[b * 4 + 0] = cntf;
            meta[b * 4 + 1] = ntiles;
            meta[b * 4 + 2] = ntiles << 6;
            meta[b * 4 + 3] = __float_as_int(cnt ? 1.f : 0.f);
        }
    }
}

// ---------------- fused Q + compacted-KV GEMM (r10 staging, locality remap) ----------------
// Compute/staging byte-identical to r10 (BK=64, single 32 KB buffer, 2 barriers/step —
// r9/r11 showed every pipelining variant regresses; the block is cache-BW bound).
// ONLY change: blockIdx -> tile mapping. Default dispatch round-robins consecutive
// bids across XCDs (xcd = bid&7). Remap so XCD x owns Q-tiles bx in [x*8, x*8+8)
// for ALL 8 by-panels: its 64 resident blocks share a 4-MB L2 working set
// (wqb 2 MB + 8 hsb tiles 2 MB) -> weight/hsb re-reads become L2 hits instead of
// cross-XCD L3 traffic. Bijective; wrong XCD assumption only costs perf.
__global__ __launch_bounds__(256)
void gemm_fused(const __bf16* __restrict__ hsb, const __bf16* __restrict__ poolb,
                const __bf16* __restrict__ wqb, const __bf16* __restrict__ wkvb,
                const float* __restrict__ bq, const float* __restrict__ bk,
                const float* __restrict__ bv, float qscale,
                const int* __restrict__ idxl, const int* __restrict__ meta,
                __bf16* __restrict__ qb, __bf16* __restrict__ kb,
                __bf16* __restrict__ vtb) {
    __shared__ __bf16 As[128 * 64];
    __shared__ __bf16 Bs[128 * 64];
    const int tid  = threadIdx.x;
    const int lane = tid & 63, wid = tid >> 6;
    const int lg = lane >> 4, l15 = lane & 15;
    const int wm = (wid >> 1) * 64, wn = (wid & 1) * 64;

    // locality remap: xcd = bid&7 (default round-robin), local = bid>>3 in [0,96)
    const int xcd = blockIdx.x & 7, local = blockIdx.x >> 3;
    const bool isQ = (local < 64);
    int bx, by, bB = 0, cntf = 0;
    if (isQ) {
        bx = xcd * 8 + (local >> 3);   // 8 bx-tiles per XCD
        by = local & 7;                // all 8 panels per XCD
    } else {
        int lid = xcd * 32 + (local - 64);   // [0,256) bijective
        bB = lid >> 7;
        bx = (lid >> 4) & 7;
        by = lid & 15;
        if (bx * 128 >= meta[bB * 4 + 2]) return;   // beyond needed compact rows
        cntf = meta[bB * 4 + 0];
    }
    const int rowBase = bx * 128, colBase = by * 128;

    const f32x4 zero = {0.f, 0.f, 0.f, 0.f};
    f32x4 acc[4][4];
#pragma unroll
    for (int m = 0; m < 4; ++m)
#pragma unroll
        for (int n = 0; n < 4; ++n) acc[m][n] = zero;

    const __bf16* W = isQ ? wqb : wkvb;
    const char* Wg = (const char*)(W + (size_t)colBase * 1024);
    char* AsB = (char*)As;
    char* BsB = (char*)Bs;

    const char* ag[4]; const char* wg[4]; int ld[4];
#pragma unroll
    for (int p = 0; p < 4; ++p) {
        int o  = p * 4096 + tid * 16;
        int r  = o >> 7, cb = o & 127;
        int cs = cb ^ ((r & 7) << 4);
        if (isQ) {
            ag[p] = (const char*)(hsb + (size_t)(rowBase + r) * 1024) + cs;
        } else {
            int rg   = rowBase + r;
            int idxg = idxl[bB * 1024 + (rg < cntf ? rg : cntf - 1)];
            ag[p] = (const char*)(poolb + (size_t)(bB * 1024 + idxg) * 1024) + cs;
        }
        wg[p] = Wg + (size_t)r * 2048 + cs;
        ld[p] = o;
    }

    for (int kt = 0; kt < 16; ++kt) {
        const int k0b = kt * 128;
        __syncthreads();
#pragma unroll
        for (int p = 0; p < 4; ++p) {
            gload16(ag[p] + k0b, AsB + ld[p]);
            gload16(wg[p] + k0b, BsB + ld[p]);
        }
        __syncthreads();

        bf16x8 af[4][2], bfr[4][2];
#pragma unroll
        for (int m = 0; m < 4; ++m)
#pragma unroll
            for (int kk = 0; kk < 2; ++kk) {
                int r  = wm + m * 16 + l15;
                int cb = kk * 64 + lg * 16;
                af[m][kk] = *(const bf16x8*)(AsB + r * 128 + (cb ^ ((r & 7) << 4)));
            }
#pragma unroll
        for (int n = 0; n < 4; ++n)
#pragma unroll
            for (int kk = 0; kk < 2; ++kk) {
                int r  = wn + n * 16 + l15;
                int cb = kk * 64 + lg * 16;
                bfr[n][kk] = *(const bf16x8*)(BsB + r * 128 + (cb ^ ((r & 7) << 4)));
            }
#pragma unroll
        for (int m = 0; m < 4; ++m)
#pragma unroll
            for (int n = 0; n < 4; ++n) {
                acc[m][n] = mfma16(af[m][0], bfr[n][0], acc[m][n]);
                acc[m][n] = mfma16(af[m][1], bfr[n][1], acc[m][n]);
            }
    }

    // epilogue. C layout: col = lane&15, row = (lane>>4)*4 + reg
#pragma unroll
    for (int m = 0; m < 4; ++m)
#pragma unroll
        for (int n = 0; n < 4; ++n) {
            int col  = colBase + wn + n * 16 + l15;
            int row0 = rowBase + wm + m * 16 + lg * 4;
            if (isQ) {
                float bvl = bq[col] * qscale;
#pragma unroll
                for (int reg = 0; reg < 4; ++reg)
                    qb[(size_t)(row0 + reg) * 1024 + col] = (__bf16)(acc[m][n][reg] + bvl);
            } else if (col < 1024) {
                float bvl = bk[col];
#pragma unroll
                for (int reg = 0; reg < 4; ++reg)
                    kb[(size_t)(bB * 1024 + row0 + reg) * 1024 + col] = (__bf16)(acc[m][n][reg] + bvl);
            } else {
                float bvl = bv[col - 1024];
                bf16x4 o;
#pragma unroll
                for (int reg = 0; reg < 4; ++reg) o[reg] = (__bf16)(acc[m][n][reg] + bvl);
                *reinterpret_cast<bf16x4*>(vtb + ((size_t)(bB * 1024 + (col - 1024)) << 10) + row0) = o;
            }
        }
}

// ---------------- flash attention over COMPACTED keys (unchanged from r8) ----------------
__global__ __launch_bounds__(256, 2)
void attn_kernel(const __bf16* __restrict__ Q, const __bf16* __restrict__ K,
                 const __bf16* __restrict__ Vt, const float* __restrict__ bias_c,
                 const int* __restrict__ meta, float* __restrict__ out) {
    __shared__ __bf16 Ks[2][64 * 64];
    __shared__ __bf16 Vs[2][64 * 64];
    __shared__ __bf16 Ps[4][64 * 64];
    const int tid  = threadIdx.x;
    const int lane = tid & 63, wid = tid >> 6;
    const int lg = lane >> 4, l15 = lane & 15;

    // XCD-aware bijective swizzle (512 blocks, 64 consecutive per XCD)
    const int lin = blockIdx.x + blockIdx.y * 16;
    const int nid = (lin & 7) * 64 + (lin >> 3);
    const int qi = nid & 15, bh = nid >> 4;
    const int b = bh >> 4, h = bh & 15;
    const int qbase = qi * 256;

    const int   ntile  = meta[b * 4 + 1];
    const float sscale = __int_as_float(meta[b * 4 + 3]);

    // Q fragments: 4 sub-tiles of 16 q rows each (A layout: row=l15, k=lg*8+j)
    bf16x8 aq[4][2];
#pragma unroll
    for (int qm = 0; qm < 4; ++qm) {
        const __bf16* qrow = Q + (((size_t)(b * 4096 + qbase + wid * 64 + qm * 16 + l15)) << 10) + h * 64;
        aq[qm][0] = *(const bf16x8*)(qrow + lg * 8);
        aq[qm][1] = *(const bf16x8*)(qrow + 32 + lg * 8);
    }

    const f32x4 zero = {0.f, 0.f, 0.f, 0.f};
    f32x4 acc[4][4];
#pragma unroll
    for (int qm = 0; qm < 4; ++qm)
#pragma unroll
        for (int n = 0; n < 4; ++n) acc[qm][n] = zero;
    float rs[4] = {0.f, 0.f, 0.f, 0.f};

    const char* Kg = (const char*)(K + (((size_t)(b * 1024)) << 10) + h * 64);
    const char* Vg = (const char*)(Vt + (((size_t)(b * 1024 + h * 64)) << 10));
    const float* mbp = bias_c + b * 1024;

    char* PsB = (char*)Ps[wid];
    const int pswz = (l15 & 7) << 4;

    const char* kg[2]; const char* vg[2]; int ld[2];
#pragma unroll
    for (int p = 0; p < 2; ++p) {
        int o  = p * 4096 + tid * 16;
        int r  = o >> 7, cb = o & 127;
        int cs = cb ^ ((r & 7) << 4);
        kg[p] = Kg + (size_t)r * 2048 + cs;
        vg[p] = Vg + (size_t)r * 2048 + cs;
        ld[p] = o;
    }

#pragma unroll
    for (int p = 0; p < 2; ++p) {
        gload16(kg[p], (char*)Ks[0] + ld[p]);
        gload16(vg[p], (char*)Vs[0] + ld[p]);
    }

    int cur = 0;
    for (int kt = 0; kt < ntile; ++kt) {
        __syncthreads();   // buf[cur] ready (vmcnt drained at barrier), buf[cur^1] free
        if (kt + 1 < ntile) {
#pragma unroll
            for (int p = 0; p < 2; ++p) {
                gload16(kg[p] + (size_t)(kt + 1) * 131072, (char*)Ks[cur ^ 1] + ld[p]);
                gload16(vg[p] + (kt + 1) * 128,            (char*)Vs[cur ^ 1] + ld[p]);
            }
        }
        const char* KsB = (const char*)Ks[cur];
        const char* VsB = (const char*)Vs[cur];

        // K fragments (reused across 4 q sub-tiles)
        bf16x8 bk[4][2];
#pragma unroll
        for (int n = 0; n < 4; ++n)
#pragma unroll
            for (int kk = 0; kk < 2; ++kk) {
                int key = n * 16 + l15;
                bk[n][kk] = *(const bf16x8*)(KsB + key * 128 + ((kk * 64 + lg * 16) ^ ((key & 7) << 4)));
            }
        f32x4 mv[4];
#pragma unroll
        for (int n = 0; n < 4; ++n) mv[n] = *(const f32x4*)(mbp + kt * 64 + n * 16 + lg * 4);

        // per q sub-tile: S^T = K·Q^T (col=q=l15, row=key=lg*4+reg), exp2, write P
#pragma unroll
        for (int qm = 0; qm < 4; ++qm) {
            f32x4 s[4];
#pragma unroll
            for (int n = 0; n < 4; ++n) {
                s[n] = mfma16(bk[n][0], aq[qm][0], zero);
                s[n] = mfma16(bk[n][1], aq[qm][1], s[n]);
            }
            const int prow = (qm * 16 + l15) * 128;
#pragma unroll
            for (int n = 0; n < 4; ++n) {
                float p0 = fast_exp2(fmaf(s[n][0], sscale, mv[n][0]));
                float p1 = fast_exp2(fmaf(s[n][1], sscale, mv[n][1]));
                float p2 = fast_exp2(fmaf(s[n][2], sscale, mv[n][2]));
                float p3 = fast_exp2(fmaf(s[n][3], sscale, mv[n][3]));
                rs[qm] += (p0 + p1) + (p2 + p3);
                bf16x4 o;
                o[0] = (__bf16)p0; o[1] = (__bf16)p1; o[2] = (__bf16)p2; o[3] = (__bf16)p3;
                *(bf16x4*)(PsB + prow + ((n * 32 + lg * 8) ^ pswz)) = o;
            }
        }

        // V fragments (reused across 4 q sub-tiles)
        bf16x8 bv[4][2];
#pragma unroll
        for (int n = 0; n < 4; ++n)
#pragma unroll
            for (int kk = 0; kk < 2; ++kk) {
                int d = n * 16 + l15;
                bv[n][kk] = *(const bf16x8*)(VsB + d * 128 + ((kk * 64 + lg * 16) ^ ((d & 7) << 4)));
            }
#pragma unroll
        for (int qm = 0; qm < 4; ++qm) {
            const int prow = (qm * 16 + l15) * 128;
            bf16x8 ap0 = *(const bf16x8*)(PsB + prow + ((lg * 16) ^ pswz));
            bf16x8 ap1 = *(const bf16x8*)(PsB + prow + ((64 + lg * 16) ^ pswz));
#pragma unroll
            for (int n = 0; n < 4; ++n) {
                acc[qm][n] = mfma16(ap0, bv[n][0], acc[qm][n]);
                acc[qm][n] = mfma16(ap1, bv[n][1], acc[qm][n]);
            }
        }
        cur ^= 1;
    }

    // reduce row sums over the 4 lane-groups, redistribute to epilogue layout
    float inv[4][4];
#pragma unroll
    for (int qm = 0; qm < 4; ++qm) {
        rs[qm] += __shfl_xor(rs[qm], 16);
        rs[qm] += __shfl_xor(rs[qm], 32);
#pragma unroll
        for (int r = 0; r < 4; ++r) inv[qm][r] = 1.0f / __shfl(rs[qm], lg * 4 + r);
    }

#pragma unroll
    for (int qm = 0; qm < 4; ++qm)
#pragma unroll
        for (int n = 0; n < 4; ++n)
#pragma unroll
            for (int r = 0; r < 4; ++r) {
                size_t row = (size_t)(b * 4096 + qbase + wid * 64 + qm * 16 + lg * 4 + r);
                out[(row << 10) + h * 64 + n * 16 + l15] = acc[qm][n][r] * inv[qm][r];
            }
}

extern "C" void kernel_launch(void* const* d_in, const int* in_sizes, int n_in,
                              void* d_out, int out_size, void* d_ws, size_t ws_size,
                              hipStream_t stream) {
    const float* hs    = (const float*)d_in[0];
    const int*   amask = (const int*)d_in[1];
    const float* Wq    = (const float*)d_in[2];
    const float* bq    = (const float*)d_in[3];
    const float* Wk    = (const float*)d_in[4];
    const float* bk    = (const float*)d_in[5];
    const float* Wv    = (const float*)d_in[6];
    const float* bv    = (const float*)d_in[7];
    float* out = (float*)d_out;

    char* ws = (char*)d_ws;
    size_t off = 0;
    auto alloc = [&](size_t bytes) -> char* {
        char* p = ws + off;
        off += (bytes + 255) & ~(size_t)255;
        return p;
    };
    __bf16* hsb   = (__bf16*)alloc(8388608ull * 2);  // hidden bf16 [8192][1024]
    __bf16* qb    = (__bf16*)alloc(8388608ull * 2);  // Q bf16 (pre-scaled)
    __bf16* poolb = (__bf16*)alloc(2097152ull * 2);  // pooled bf16 [2048][1024]
    __bf16* kb    = (__bf16*)alloc(2097152ull * 2);  // K compact [b][key_c][1024]
    __bf16* vtb   = (__bf16*)alloc(2097152ull * 2);  // V^T compact [b][h*64+d][key_c]
    __bf16* wqb   = (__bf16*)alloc(1048576ull * 2);  // Wq * qscale
    __bf16* wkvb  = (__bf16*)alloc(2097152ull * 2);  // [Wk ; Wv]
    int*    idxl  = (int*)alloc(2048 * 4);           // compact index lists
    float*  biasc = (float*)alloc(2048 * 4);         // tail-validity bias
    int*    meta  = (int*)alloc(8 * 4);

    const float qscale = 0.125f * LOG2E;   // 1/sqrt(DH) and log2(e) folded into Q

    prep_kernel<<<2562, 256, 0, stream>>>(hs, amask, Wq, Wk, Wv, hsb, poolb,
                                          wqb, wkvb, idxl, biasc, meta, qscale);

    gemm_fused<<<768, 256, 0, stream>>>(hsb, poolb, wqb, wkvb, bq, bk, bv, qscale,
                                        idxl, meta, qb, kb, vtb);

    attn_kernel<<<dim3(16, 32), 256, 0, stream>>>(qb, kb, vtb, biasc, meta, out);
}